// Round 1
// baseline (255.721 us; speedup 1.0000x reference)
//
#include <hip/hip_runtime.h>

// BCE loss reduction over (64,8,65536,1) fp32 pred/true.
// loss = -sum(t*max(log p,-100) + (1-t)*max(log(1-p),-100)) / (65536*64)
// log2-domain: bce_elem = lq + t*(lp-lq); scale by -ln2/4194304 at the end.
//
// R9: single variable vs R8 = read cache policy sc0+sc1+nt (full bypass)
// instead of nt-only.
// Post-mortem model (R1-R8): read streams capped by per-CU in-flight-line
// limit x HBM latency (~5.6 B/cyc/CU with nt; 4 structural variants and
// LDS-DMA all identical; write-only fill hits 6.8 TB/s). nt lifted
// 2.6->3.4 TB/s by easing L1 allocation pressure; sc0+sc1 additionally
// skips L1 and the (zero-hit, non-coherent per-XCD) L2 entirely.
// __builtin_nontemporal_load can't set sc bits -> inline-asm
// global_load_dwordx4 with manual depth-2 pipeline: counted vmcnt(2)
// waits + sched_barrier(0) after each wait (guide rule #18: hipcc hoists
// pure-FP compute past inline-asm waitcnt otherwise).
// Prediction: kernel ~78 -> ~55-62 us if theory right => dur_us ~230-238
// (remaining ~158 us is harness poison fills, not ours). Flat => cap is a
// shared miss queue independent of allocation policy.

#define LOG2_CLAMP -144.26950408889634f   // -100 / ln(2)

typedef float vfloat4 __attribute__((ext_vector_type(4)));

__device__ __forceinline__ void bce4_acc(vfloat4 p, vfloat4 t,
                                         float& sq, float& sd) {
    float lp, lq;
    lp = fmaxf(__log2f(p.x), LOG2_CLAMP);
    lq = fmaxf(__log2f(1.0f - p.x), LOG2_CLAMP);   // 1-p exact for p>=0.5
    sq += lq; sd = __builtin_fmaf(t.x, lp - lq, sd);
    lp = fmaxf(__log2f(p.y), LOG2_CLAMP);
    lq = fmaxf(__log2f(1.0f - p.y), LOG2_CLAMP);
    sq += lq; sd = __builtin_fmaf(t.y, lp - lq, sd);
    lp = fmaxf(__log2f(p.z), LOG2_CLAMP);
    lq = fmaxf(__log2f(1.0f - p.z), LOG2_CLAMP);
    sq += lq; sd = __builtin_fmaf(t.z, lp - lq, sd);
    lp = fmaxf(__log2f(p.w), LOG2_CLAMP);
    lq = fmaxf(__log2f(1.0f - p.w), LOG2_CLAMP);
    sq += lq; sd = __builtin_fmaf(t.w, lp - lq, sd);
}

// Streaming read: bypass L1 (sc0) and non-coherent per-XCD L2 (sc1),
// non-temporal (nt). SGPR base + 32-bit VGPR byte offset (<128 MiB here).
__device__ __forceinline__ vfloat4 ld_bypass(const float* __restrict__ base,
                                             unsigned byte_off) {
    vfloat4 r;
    asm volatile("global_load_dwordx4 %0, %1, %2 sc0 sc1 nt"
                 : "=v"(r)
                 : "v"(byte_off), "s"(base));
    return r;
}

// Counted drain + scheduler fence (rule #18). n must be a literal.
#define WAITCNT(n) do {                                            \
        asm volatile("s_waitcnt vmcnt(" #n ")" ::: "memory");      \
        __builtin_amdgcn_sched_barrier(0);                         \
    } while (0)

__global__ __launch_bounds__(256) void vertical_loss_kernel(
    const float* __restrict__ pf,
    const float* __restrict__ tf,
    float* __restrict__ out,
    int n4, float final_scale)
{
    float sq = 0.0f, sd = 0.0f;

    const int chunk = n4 / (int)gridDim.x;           // float4s per block
    const int steps = chunk / (int)blockDim.x;       // iterations per thread

    const bool fast = ((n4 % (int)gridDim.x) == 0) &&
                      ((chunk % (int)blockDim.x) == 0) &&
                      (steps >= 2) && ((steps & 1) == 0);

    if (fast) {
        // Block-contiguous tiles (identical addressing to R8). Depth-2
        // register pipeline: 4 loads in flight per wave; with 32 waves/CU
        // the CU-level read queue stays saturated.
        const unsigned stride = (unsigned)blockDim.x * 16u;        // 4096 B
        unsigned off = ((unsigned)blockIdx.x * (unsigned)chunk +
                        threadIdx.x) * 16u;

        vfloat4 pA = ld_bypass(pf, off);
        vfloat4 tA = ld_bypass(tf, off);
        vfloat4 pB = ld_bypass(pf, off + stride);
        vfloat4 tB = ld_bypass(tf, off + stride);
        unsigned offI = off + 2u * stride;           // next issue offset

        int s = 0;
        for (; s + 4 <= steps; s += 2) {
            WAITCNT(2);                              // pair A (oldest) done
            bce4_acc(pA, tA, sq, sd);
            pA = ld_bypass(pf, offI);
            tA = ld_bypass(tf, offI);
            offI += stride;
            WAITCNT(2);                              // pair B done
            bce4_acc(pB, tB, sq, sd);
            pB = ld_bypass(pf, offI);
            tB = ld_bypass(tf, offI);
            offI += stride;
        }
        WAITCNT(2);                                  // steps-2 pair
        bce4_acc(pA, tA, sq, sd);
        WAITCNT(0);                                  // steps-1 pair
        bce4_acc(pB, tB, sq, sd);
    } else {
        // Generic fallback (not taken for the bench shape).
        const vfloat4* p4 = (const vfloat4*)pf;
        const vfloat4* t4 = (const vfloat4*)tf;
        for (int i = (int)blockIdx.x * (int)blockDim.x + (int)threadIdx.x;
             i < n4; i += (int)gridDim.x * (int)blockDim.x) {
            vfloat4 p = __builtin_nontemporal_load(&p4[i]);
            vfloat4 t = __builtin_nontemporal_load(&t4[i]);
            bce4_acc(p, t, sq, sd);
        }
    }

    float sum = sq + sd;

    // wave (64-lane) reduction
    #pragma unroll
    for (int off = 32; off > 0; off >>= 1)
        sum += __shfl_down(sum, off, 64);

    __shared__ float wsum[4];  // 256 threads = 4 waves
    int wave = threadIdx.x >> 6;
    int lane = threadIdx.x & 63;
    if (lane == 0) wsum[wave] = sum;
    __syncthreads();

    if (threadIdx.x == 0) {
        float fs = wsum[0] + wsum[1] + wsum[2] + wsum[3];
        atomicAdd(out, fs * final_scale);  // device-scope by default on CDNA
    }
}

extern "C" void kernel_launch(void* const* d_in, const int* in_sizes, int n_in,
                              void* d_out, int out_size, void* d_ws, size_t ws_size,
                              hipStream_t stream) {
    const float* pred  = (const float*)d_in[0];
    const float* true_ = (const float*)d_in[1];
    float* out = (float*)d_out;

    int n  = in_sizes[0];   // 33,554,432 elements
    int n4 = n / 4;         // 8,388,608 float4s
    // loss = -ln2 * (sq+sd)_total / (65536*64)
    float final_scale = -0.69314718055994531f / (65536.0f * 64.0f);

    // Harness re-poisons d_out with 0xAA before every launch — zero it.
    (void)hipMemsetAsync(d_out, 0, sizeof(float), stream);

    // 2048 blocks x 256 threads: contiguous 4096-float4 chunk per block,
    // 16 iterations/thread; 32 waves/CU. Unchanged vs R8 — the only
    // variable this round is the load cache policy.
    int blocks = 2048;
    vertical_loss_kernel<<<blocks, 256, 0, stream>>>(pred, true_, out, n4, final_scale);
}